// Round 16
// baseline (147.136 us; speedup 1.0000x reference)
//
#include <hip/hip_runtime.h>
#include <hip/hip_bf16.h>
#include <stdint.h>

// Problem constants (LinearRNN): B=16, T=4096, D_IN=256, HID=512, D_OUT=256
#define BATCH 16
#define SEQT  4096
#define DIN   256
#define HID   512
#define DOUT  256
#define M_TOT 65536
#define CLEN  128                 // chunk length (== GEMM m-tile)
#define NCHUNK 32                 // SEQT / CLEN

typedef short bf16x8 __attribute__((ext_vector_type(8)));
typedef float f32x4  __attribute__((ext_vector_type(4)));
typedef unsigned short u16;
typedef unsigned short u16x4 __attribute__((ext_vector_type(4)));
typedef unsigned int uint32;

// async global->LDS, 16B per lane; LDS dest is wave-uniform base + lane*16
__device__ __forceinline__ void ld_lds16(const void* g, void* l) {
    __builtin_amdgcn_global_load_lds(
        (const __attribute__((address_space(1))) void*)g,
        (__attribute__((address_space(3))) void*)l, 16, 0, 0);
}

__device__ __forceinline__ u16 f2bf_rne(float f) {
    uint32 v = __float_as_uint(f);
    v += 0x7FFFu + ((v >> 16) & 1u);
    return (u16)(v >> 16);
}

__device__ __forceinline__ float bf2f(u16 s) {
    return __uint_as_float((uint32)s << 16);
}

// trunc-hi / rne-lo split: f ~= hi + lo, ~17-bit combined mantissa
__device__ __forceinline__ void splitf(float f, u16& hi, u16& lo) {
    const uint32 u = __float_as_uint(f);
    hi = (u16)(u >> 16);
    lo = f2bf_rne(f - __uint_as_float(u & 0xFFFF0000u));
}

// ---------------------------------------------------------------------------
// prep: block 0 -> wdiag + wpow (w^(tl+1), tl<128); blocks 1..128 -> W_in
// split; blocks 129..256 -> W_out split.
// ---------------------------------------------------------------------------
__global__ __launch_bounds__(256) void prep(
        const float* __restrict__ Wh, const float* __restrict__ Win,
        const float* __restrict__ Wout, float* __restrict__ wdiag,
        float* __restrict__ wpow, u16* __restrict__ Winhi,
        u16* __restrict__ Winlo, u16* __restrict__ Wouthi,
        u16* __restrict__ Woutlo) {
    const int bid = blockIdx.x, tid = threadIdx.x;
    if (bid == 0) {
        for (int h = tid; h < HID; h += 256) {
            const float wv = Wh[(size_t)h * HID + h];
            wdiag[h] = wv;
            float p = 1.f;
            for (int t = 0; t < CLEN; ++t) { p *= wv; wpow[t * HID + h] = p; }
        }
    } else if (bid <= 128) {
        const int f4 = (bid - 1) * 256 + tid;   // < 32768
        const f32x4 v = *(const f32x4*)(Win + (size_t)f4 * 4);
        u16x4 hv, lv;
#pragma unroll
        for (int k = 0; k < 4; ++k) { u16 a, b; splitf(v[k], a, b); hv[k] = a; lv[k] = b; }
        *(u16x4*)(Winhi + (size_t)f4 * 4) = hv;
        *(u16x4*)(Winlo + (size_t)f4 * 4) = lv;
    } else {
        const int f4 = (bid - 129) * 256 + tid;
        const f32x4 v = *(const f32x4*)(Wout + (size_t)f4 * 4);
        u16x4 hv, lv;
#pragma unroll
        for (int k = 0; k < 4; ++k) { u16 a, b; splitf(v[k], a, b); hv[k] = a; lv[k] = b; }
        *(u16x4*)(Wouthi + (size_t)f4 * 4) = hv;
        *(u16x4*)(Woutlo + (size_t)f4 * 4) = lv;
    }
}

// ---------------------------------------------------------------------------
// GEMM1 + in-register scan. Tile 128m x 256n, 512 threads = 8 waves
// (2 wr x 4 wc of 64x64 quadrants; acc[4][4] = 64 VGPR; read:MFMA ratio 3).
// BK=32: rows are 64B (4 x 16B granules) -> natural bank interleave, NO
// swizzle needed. Staging ~48KB, total LDS 69.6KB -> 2 blocks/CU = 16 waves.
// Epilogue: R11's verified 64x64-wave register scan + stb transpose + 512B
// coalesced rows. Both n-halves of an m-tile land on the same XCD.
// Grid: 1024 linear, XCD-swizzled.
// ---------------------------------------------------------------------------
__global__ __launch_bounds__(512, 2) void gemm1_scan(
        const float* __restrict__ X, const u16* __restrict__ Whi,
        const u16* __restrict__ Wlo, u16* __restrict__ localbf,
        float* __restrict__ L, const float* __restrict__ wdiag) {
    __shared__ __align__(16) char smem[69632];
    u16*   Ah  = (u16*)smem;                 // [128][32] u16, 8KB
    u16*   Al  = (u16*)(smem + 8192);        // 8KB
    u16*   Bh  = (u16*)(smem + 16384);       // [256][32] u16, 16KB
    u16*   Bl  = (u16*)(smem + 32768);       // 16KB  (staging total 48KB)
    u16*   stb = (u16*)smem;                 // [128][264] u16, 67584B (aliases)
    float* xw  = (float*)(smem + 67584);     // [256] f32, 1KB (no alias)

    const int tid  = threadIdx.x;
    const int w    = tid >> 6;               // 0..7
    const int lane = tid & 63;

    // XCD swizzle: bid = slot*8 + xcd; slot = (m-tile, n-half)
    const int bid  = blockIdx.x;
    const int xcd  = bid & 7;
    const int slot = bid >> 3;               // 0..127
    const int mBase = (xcd * 64 + (slot >> 1)) * 128;
    const int nBase = (slot & 1) * 256;

    const int wr = w >> 2;                   // 0..1 (64-row half)
    const int wc = w & 3;                    // 0..3 (64-col quadrant)
    const int fr = lane & 15;
    const int kg = lane >> 4;

    // A staging: thread -> one 32B granule (8 f32): r_a = tid>>2, g_a = tid&3
    const int r_a = tid >> 2;
    const int g_a = tid & 3;

    // B staging: per ld_lds16, 16 rows x 4 granules (lane: rl = l>>2, pg = l&3)
    const int rl = lane >> 2;
    const int pg = lane & 3;

    f32x4 acc[4][4];
#pragma unroll
    for (int i = 0; i < 4; ++i)
#pragma unroll
        for (int j = 0; j < 4; ++j) acc[i][j] = (f32x4){0.f, 0.f, 0.f, 0.f};

    for (int kk = 0; kk < 8; ++kk) {
        const int k0 = kk * 32;
        // B: 256 rows hi+lo via global_load_lds (issued first)
#pragma unroll
        for (int q = 0; q < 2; ++q) {
            const int c = w * 2 + q;         // 16 chunks of 16 rows
            const int row = nBase + c * 16 + rl;
            ld_lds16(Whi + (size_t)row * DIN + k0 + pg * 8, Bh + c * 512);
            ld_lds16(Wlo + (size_t)row * DIN + k0 + pg * 8, Bl + c * 512);
        }
        // A: one granule per thread, split once, straight ds_write
        {
            const float* src = X + (size_t)(mBase + r_a) * DIN + k0 + g_a * 8;
            const f32x4 v0 = *(const f32x4*)(src);
            const f32x4 v1 = *(const f32x4*)(src + 4);
            bf16x8 h8, l8;
#pragma unroll
            for (int e = 0; e < 4; ++e) {
                u16 a, b;
                splitf(v0[e], a, b); h8[e] = (short)a; l8[e] = (short)b;
                splitf(v1[e], a, b); h8[e + 4] = (short)a; l8[e + 4] = (short)b;
            }
            *(bf16x8*)(Ah + r_a * 32 + g_a * 8) = h8;
            *(bf16x8*)(Al + r_a * 32 + g_a * 8) = l8;
        }
        __syncthreads();

        // MFMA phase: K=32 (kg selects the 8-elem k-group), 48 MFMA/wave
        bf16x8 ah[4], al[4];
#pragma unroll
        for (int i = 0; i < 4; ++i) {
            const int sa = (wr * 64 + i * 16 + fr) * 32 + kg * 8;
            ah[i] = *(const bf16x8*)(Ah + sa);
            al[i] = *(const bf16x8*)(Al + sa);
        }
#pragma unroll
        for (int j = 0; j < 4; ++j) {
            const int sb = (wc * 64 + j * 16 + fr) * 32 + kg * 8;
            const bf16x8 bh = *(const bf16x8*)(Bh + sb);
            const bf16x8 bl = *(const bf16x8*)(Bl + sb);
#pragma unroll
            for (int i = 0; i < 4; ++i) {
                acc[i][j] = __builtin_amdgcn_mfma_f32_16x16x32_bf16(ah[i], bh, acc[i][j], 0, 0, 0);
                acc[i][j] = __builtin_amdgcn_mfma_f32_16x16x32_bf16(ah[i], bl, acc[i][j], 0, 0, 0);
                acc[i][j] = __builtin_amdgcn_mfma_f32_16x16x32_bf16(al[i], bh, acc[i][j], 0, 0, 0);
            }
        }
        __syncthreads();
    }

    // ---- in-register scan along t (rows), verified (R11). C/D layout:
    // row = wr*64 + i*16 + kg*4 + rg, col = wc*64 + j*16 + fr ----
    float w1[4], w2[4], w3[4], w4[4], w8[4], w16[4];
#pragma unroll
    for (int j = 0; j < 4; ++j) {
        const float wv = wdiag[nBase + wc * 64 + j * 16 + fr];
        w1[j] = wv; w2[j] = wv * wv; w3[j] = w2[j] * wv; w4[j] = w2[j] * w2[j];
        w8[j] = w4[j] * w4[j]; w16[j] = w8[j] * w8[j];
    }
    float Bst[4] = {0.f, 0.f, 0.f, 0.f};   // running state per j (64-row half)
#pragma unroll
    for (int i = 0; i < 4; ++i) {
#pragma unroll
        for (int j = 0; j < 4; ++j) {
            // 4-row local scan (zero incoming)
            const float l0 = acc[i][j][0];
            const float l1 = fmaf(w1[j], l0, acc[i][j][1]);
            const float l2 = fmaf(w1[j], l1, acc[i][j][2]);
            const float l3 = fmaf(w1[j], l2, acc[i][j][3]);
            // gather the 4 kg-segment totals for this column
            const float x0 = __shfl(l3, fr);
            const float x1 = __shfl(l3, fr + 16);
            const float x2 = __shfl(l3, fr + 32);
            const float x3 = __shfl(l3, fr + 48);
            // incoming state for own kg + running 64-half state
            float s = Bst[j];
            float S = s;
            s = fmaf(w4[j], s, x0); S = (kg == 1) ? s : S;
            s = fmaf(w4[j], s, x1); S = (kg == 2) ? s : S;
            s = fmaf(w4[j], s, x2); S = (kg == 3) ? s : S;
            s = fmaf(w4[j], s, x3);
            Bst[j] = s;
            // correct own 4 rows
            acc[i][j][0] = fmaf(w1[j], S, l0);
            acc[i][j][1] = fmaf(w2[j], S, l1);
            acc[i][j][2] = fmaf(w3[j], S, l2);
            acc[i][j][3] = fmaf(w4[j], S, l3);
        }
    }
    // cross-half (row 63 -> 64) exchange
    if (wr == 0 && kg == 0) {
#pragma unroll
        for (int j = 0; j < 4; ++j) xw[wc * 64 + j * 16 + fr] = Bst[j];
    }
    __syncthreads();
    if (wr == 1) {
        const int cI = (mBase >> 7) & (NCHUNK - 1);
        const int bI = mBase >> 12;
#pragma unroll
        for (int j = 0; j < 4; ++j) {
            const float cin = xw[wc * 64 + j * 16 + fr];
            float wkg = 1.f;
            if (kg & 1) wkg *= w4[j];
            if (kg & 2) wkg *= w8[j];
            float f = wkg;                   // w^(16i + 4kg)
#pragma unroll
            for (int i = 0; i < 4; ++i) {
                const float g = f * cin;
                acc[i][j][0] = fmaf(w1[j], g, acc[i][j][0]);
                acc[i][j][1] = fmaf(w2[j], g, acc[i][j][1]);
                acc[i][j][2] = fmaf(w3[j], g, acc[i][j][2]);
                acc[i][j][3] = fmaf(w4[j], g, acc[i][j][3]);
                f *= w16[j];
            }
            if (kg == 0) {
                const float w32 = w16[j] * w16[j];
                const float w64 = w32 * w32;
                L[(cI * BATCH + bI) * HID + nBase + wc * 64 + j * 16 + fr]
                    = fmaf(w64, cin, Bst[j]);
            }
        }
    }
    __syncthreads();   // staging dead; stb may overwrite

    // bf16 scatter into LDS transpose buffer (stride 264 over 256 cols)
#pragma unroll
    for (int i = 0; i < 4; ++i)
#pragma unroll
        for (int j = 0; j < 4; ++j)
#pragma unroll
            for (int rg = 0; rg < 4; ++rg)
                stb[(wr * 64 + i * 16 + kg * 4 + rg) * 264
                    + wc * 64 + j * 16 + fr] = f2bf_rne(acc[i][j][rg]);
    __syncthreads();

    // coalesced readout: 128 rows x 256 cols, 512B contiguous per row
#pragma unroll
    for (int it = 0; it < 8; ++it) {
        const int idx = it * 512 + tid;      // 0..4095 granules of 8 u16
        const int row = idx >> 5, g = idx & 31;
        const bf16x8 v = *(const bf16x8*)(stb + row * 264 + g * 8);
        *(bf16x8*)(localbf + (size_t)(mBase + row) * HID + nBase + g * 8) = v;
    }
}

// ---------------------------------------------------------------------------
// carry across chunks: carry[c][b][h] = state entering chunk c
// ---------------------------------------------------------------------------
__global__ __launch_bounds__(256) void scan_carry(
        const float* __restrict__ L, const float* __restrict__ wpow,
        float* __restrict__ carry) {
    const int idx = blockIdx.x * 256 + threadIdx.x;   // 8192
    const int h = idx & (HID - 1);
    const int b = idx >> 9;
    const float wf = wpow[(CLEN - 1) * HID + h];      // w^128
    float H = 0.f;
    for (int c = 0; c < NCHUNK; ++c) {
        const int o = (c * BATCH + b) * HID + h;
        carry[o] = H;
        H = fmaf(wf, H, L[o]);
    }
}

// ---------------------------------------------------------------------------
// GEMM2 with fused fix: out = (local_bf16 + w^(tl+1)*carry) @ W_out^T.
// (unchanged from R8 — ~80% MFMA-pipe-bound, at structural ceiling)
// ---------------------------------------------------------------------------
__global__ __launch_bounds__(256, 2) void gemm2_fix(
        const u16* __restrict__ localbf, const u16* __restrict__ Bhi_g,
        const u16* __restrict__ Blo_g, const float* __restrict__ wpow,
        const float* __restrict__ carry, float* __restrict__ C) {
    __shared__ __align__(16) char smem[65536];
    u16* Ah = (u16*)smem;                   // [128][64] swizzled (16KB)
    u16* Al = (u16*)(smem + 16384);
    u16* Bh = (u16*)(smem + 32768);
    u16* Bl = (u16*)(smem + 49152);

    const int tid  = threadIdx.x;
    const int w    = tid >> 6;
    const int lane = tid & 63;

    const int bid  = blockIdx.x;
    const int xcd  = bid & 7;
    const int slot = bid >> 3;              // 0..127
    const int mBase = (xcd * 64 + (slot >> 1)) * 128;
    const int nBase = (slot & 1) * 128;

    const int wr = w >> 1, wc = w & 1;
    const int fr = lane & 15;
    const int kg = lane >> 4;

    const int bRow = lane >> 3;
    const int bCol = ((lane & 7) ^ bRow) * 8;

    // fix constants: whole m-tile is one (chunk, batch)
    const int cI = (mBase >> 7) & (NCHUNK - 1);
    const int bI = mBase >> 12;
    const float* crow = carry + (size_t)(cI * BATCH + bI) * HID;

    f32x4 acc[4][4];
#pragma unroll
    for (int i = 0; i < 4; ++i)
#pragma unroll
        for (int j = 0; j < 4; ++j) acc[i][j] = (f32x4){0.f, 0.f, 0.f, 0.f};

    for (int k0 = 0; k0 < HID; k0 += 64) {
        // B: async global->LDS FIRST (latency hides under A staging)
#pragma unroll
        for (int i = 0; i < 4; ++i) {
            const int c = w * 4 + i;
            const int r2 = c * 8 + bRow;
            ld_lds16(Bhi_g + (size_t)(nBase + r2) * HID + k0 + bCol, Bh + c * 512);
            ld_lds16(Blo_g + (size_t)(nBase + r2) * HID + k0 + bCol, Bl + c * 512);
        }
        // A: reg-staged, bf16 load + fix + split fused
#pragma unroll
        for (int it = 0; it < 4; ++it) {
            const int idx = it * 256 + tid;   // 0..1023 granules of 8 bf16
            const int r  = idx >> 3;          // 0..127 (tl == r)
            const int gl = idx & 7;
            const int gm = mBase + r;
            const size_t col = (size_t)(k0 + gl * 8);
            const bf16x8 lv = *(const bf16x8*)(localbf + (size_t)gm * HID + col);
            const f32x4 p0 = *(const f32x4*)(wpow + (size_t)r * HID + col);
            const f32x4 p1 = *(const f32x4*)(wpow + (size_t)r * HID + col + 4);
            const f32x4 c0 = *(const f32x4*)(crow + col);
            const f32x4 c1 = *(const f32x4*)(crow + col + 4);
            bf16x8 h8, l8;
#pragma unroll
            for (int e = 0; e < 4; ++e) {
                const float f0 = fmaf(p0[e], c0[e], bf2f((u16)lv[e]));
                const float f1 = fmaf(p1[e], c1[e], bf2f((u16)lv[e + 4]));
                u16 a, b;
                splitf(f0, a, b); h8[e] = (short)a; l8[e] = (short)b;
                splitf(f1, a, b); h8[e + 4] = (short)a; l8[e + 4] = (short)b;
            }
            const int phys = r * 64 + ((gl ^ (r & 7)) * 8);
            *(bf16x8*)(Ah + phys) = h8;
            *(bf16x8*)(Al + phys) = l8;
        }
        __syncthreads();
#pragma unroll
        for (int ks = 0; ks < 2; ++ks) {
            const int colE = ks * 32 + kg * 8;
            bf16x8 ah[4], al[4], bh[4], bl[4];
#pragma unroll
            for (int f = 0; f < 4; ++f) {
                const int ra = wr * 64 + f * 16 + fr;
                const int pa = ra * 64 + (colE ^ ((fr & 7) << 3));
                ah[f] = *(const bf16x8*)(Ah + pa);
                al[f] = *(const bf16x8*)(Al + pa);
                const int rb = wc * 64 + f * 16 + fr;
                const int pb = rb * 64 + (colE ^ ((fr & 7) << 3));
                bh[f] = *(const bf16x8*)(Bh + pb);
                bl[f] = *(const bf16x8*)(Bl + pb);
            }
#pragma unroll
            for (int i = 0; i < 4; ++i)
#pragma unroll
                for (int j = 0; j < 4; ++j) {
                    acc[i][j] = __builtin_amdgcn_mfma_f32_16x16x32_bf16(ah[i], bh[j], acc[i][j], 0, 0, 0);
                    acc[i][j] = __builtin_amdgcn_mfma_f32_16x16x32_bf16(ah[i], bl[j], acc[i][j], 0, 0, 0);
                    acc[i][j] = __builtin_amdgcn_mfma_f32_16x16x32_bf16(al[i], bh[j], acc[i][j], 0, 0, 0);
                }
        }
        __syncthreads();
    }

#pragma unroll
    for (int i = 0; i < 4; ++i) {
        const size_t row0 = (size_t)mBase + wr * 64 + i * 16 + kg * 4;
#pragma unroll
        for (int j = 0; j < 4; ++j) {
            const int col = nBase + wc * 64 + j * 16 + fr;
#pragma unroll
            for (int rg = 0; rg < 4; ++rg)
                C[(row0 + rg) * DOUT + col] = acc[i][j][rg];
        }
    }
}

// ---------------------------------------------------------------------------
extern "C" void kernel_launch(void* const* d_in, const int* in_sizes, int n_in,
                              void* d_out, int out_size, void* d_ws, size_t ws_size,
                              hipStream_t stream) {
    const float* x     = (const float*)d_in[0];   // [16,4096,256]
    const float* W_in  = (const float*)d_in[1];   // [512,256]
    const float* W_h   = (const float*)d_in[2];   // [512,512] (diagonal)
    const float* W_out = (const float*)d_in[3];   // [256,512]
    float* out = (float*)d_out;                    // [16,4096,256]

    // workspace layout
    char* ws = (char*)d_ws;
    u16*   localbf = (u16*)(ws);                       // 67,108,864 (bf16 local state)
    float* L       = (float*)(ws + 134217728);         // 1,048,576
    float* carry   = (float*)(ws + 135266304);         // 1,048,576
    float* wpow    = (float*)(ws + 136314880);         // 262,144
    float* wdiag   = (float*)(ws + 136577024);         // 2,048
    u16*   Winhi   = (u16*)(ws + 136579072);           // 262,144
    u16*   Winlo   = (u16*)(ws + 136841216);           // 262,144
    u16*   Wouthi  = (u16*)(ws + 137103360);           // 262,144
    u16*   Woutlo  = (u16*)(ws + 137365504);           // 262,144

    prep<<<257, 256, 0, stream>>>(W_h, W_in, W_out, wdiag, wpow,
                                  Winhi, Winlo, Wouthi, Woutlo);
    gemm1_scan<<<1024, 512, 0, stream>>>(x, Winhi, Winlo, localbf, L, wdiag);
    scan_carry<<<32, 256, 0, stream>>>(L, wpow, carry);
    gemm2_fix<<<1024, 256, 0, stream>>>(localbf, Wouthi, Woutlo, wpow, carry, out);
}

// Round 17
// 127.865 us; speedup vs baseline: 1.1507x; 1.1507x over previous
//
#include <hip/hip_runtime.h>
#include <hip/hip_bf16.h>
#include <stdint.h>

// Problem constants (LinearRNN): B=16, T=4096, D_IN=256, HID=512, D_OUT=256
#define BATCH 16
#define SEQT  4096
#define DIN   256
#define HID   512
#define DOUT  256
#define M_TOT 65536
#define CLEN  128                 // chunk length (== GEMM m-tile)
#define NCHUNK 32                 // SEQT / CLEN

typedef short bf16x8 __attribute__((ext_vector_type(8)));
typedef float f32x4  __attribute__((ext_vector_type(4)));
typedef unsigned short u16;
typedef unsigned short u16x4 __attribute__((ext_vector_type(4)));
typedef unsigned int uint32;

// async global->LDS, 16B per lane; LDS dest is wave-uniform base + lane*16
__device__ __forceinline__ void ld_lds16(const void* g, void* l) {
    __builtin_amdgcn_global_load_lds(
        (const __attribute__((address_space(1))) void*)g,
        (__attribute__((address_space(3))) void*)l, 16, 0, 0);
}

__device__ __forceinline__ u16 f2bf_rne(float f) {
    uint32 v = __float_as_uint(f);
    v += 0x7FFFu + ((v >> 16) & 1u);
    return (u16)(v >> 16);
}

__device__ __forceinline__ float bf2f(u16 s) {
    return __uint_as_float((uint32)s << 16);
}

// trunc-hi / rne-lo split: f ~= hi + lo, ~17-bit combined mantissa
__device__ __forceinline__ void splitf(float f, u16& hi, u16& lo) {
    const uint32 u = __float_as_uint(f);
    hi = (u16)(u >> 16);
    lo = f2bf_rne(f - __uint_as_float(u & 0xFFFF0000u));
}

// ---------------------------------------------------------------------------
// prep: block 0 -> wdiag + wpow (w^(tl+1), tl<128); blocks 1..128 -> W_in
// split; blocks 129..256 -> W_out split.
// ---------------------------------------------------------------------------
__global__ __launch_bounds__(256) void prep(
        const float* __restrict__ Wh, const float* __restrict__ Win,
        const float* __restrict__ Wout, float* __restrict__ wdiag,
        float* __restrict__ wpow, u16* __restrict__ Winhi,
        u16* __restrict__ Winlo, u16* __restrict__ Wouthi,
        u16* __restrict__ Woutlo) {
    const int bid = blockIdx.x, tid = threadIdx.x;
    if (bid == 0) {
        for (int h = tid; h < HID; h += 256) {
            const float wv = Wh[(size_t)h * HID + h];
            wdiag[h] = wv;
            float p = 1.f;
            for (int t = 0; t < CLEN; ++t) { p *= wv; wpow[t * HID + h] = p; }
        }
    } else if (bid <= 128) {
        const int f4 = (bid - 1) * 256 + tid;   // < 32768
        const f32x4 v = *(const f32x4*)(Win + (size_t)f4 * 4);
        u16x4 hv, lv;
#pragma unroll
        for (int k = 0; k < 4; ++k) { u16 a, b; splitf(v[k], a, b); hv[k] = a; lv[k] = b; }
        *(u16x4*)(Winhi + (size_t)f4 * 4) = hv;
        *(u16x4*)(Winlo + (size_t)f4 * 4) = lv;
    } else {
        const int f4 = (bid - 129) * 256 + tid;
        const f32x4 v = *(const f32x4*)(Wout + (size_t)f4 * 4);
        u16x4 hv, lv;
#pragma unroll
        for (int k = 0; k < 4; ++k) { u16 a, b; splitf(v[k], a, b); hv[k] = a; lv[k] = b; }
        *(u16x4*)(Wouthi + (size_t)f4 * 4) = hv;
        *(u16x4*)(Woutlo + (size_t)f4 * 4) = lv;
    }
}

// ---------------------------------------------------------------------------
// GEMM1 + fused segmented scan (R8 configuration — session best).
// xp = x @ W_in^T per 128x128 tile (tile rows == one full chunk), then
// 3-phase segmented scan (x4-vectorized), write BF16 chunk-local state
// (halves intermediate HBM traffic) + fp32 chunk-final L.
// A-path: reg-staged (global f32 -> split once -> swizzled ds_write), B-path
// global_load_lds issued FIRST so its HBM latency hides under A staging.
// Grid: 2048 linear, XCD-swizzled.
// ---------------------------------------------------------------------------
__global__ __launch_bounds__(256, 2) void gemm1_scan(
        const float* __restrict__ X, const u16* __restrict__ Whi,
        const u16* __restrict__ Wlo, u16* __restrict__ localbf,
        float* __restrict__ L, const float* __restrict__ wdiag,
        const float* __restrict__ wpow) {
    __shared__ __align__(16) char smem[75776];
    u16*   Ah = (u16*)smem;                 // [128][64] bf16 hi, swizzled (16KB)
    u16*   Al = (u16*)(smem + 16384);       // lo (16KB)
    u16*   Bh = (u16*)(smem + 32768);       // [128][64] bf16, swizzled (16KB)
    u16*   Bl = (u16*)(smem + 49152);       // 16KB
    float* st = (float*)smem;               // scan tile [128][132] f32 (aliased, 66KB)
    float* segT = (float*)(smem + 67584);   // [8][128] seg totals (4KB)
    float* segC = (float*)(smem + 71680);   // [8][128] seg carries (4KB)

    const int tid  = threadIdx.x;
    const int w    = tid >> 6;
    const int lane = tid & 63;

    // XCD swizzle: 8 XCDs x 256 slots; slot = (m within xcd-run, n)
    const int bid  = blockIdx.x;
    const int xcd  = bid & 7;
    const int slot = bid >> 3;              // 0..255
    const int mBase = (xcd * 64 + (slot >> 2)) * 128;
    const int nBase = (slot & 3) * 128;

    const int wr = w >> 1, wc = w & 1;
    const int fr = lane & 15;
    const int kg = lane >> 4;

    const int bRow = lane >> 3;                        // row within 8-row chunk
    const int bCol = ((lane & 7) ^ bRow) * 8;          // pre-swizzled col (u16)

    f32x4 acc[4][4];
#pragma unroll
    for (int i = 0; i < 4; ++i)
#pragma unroll
        for (int j = 0; j < 4; ++j) acc[i][j] = (f32x4){0.f, 0.f, 0.f, 0.f};

    for (int k0 = 0; k0 < DIN; k0 += 64) {
        // B bf16 hi/lo FIRST (async; latency hides under A staging below)
#pragma unroll
        for (int i = 0; i < 4; ++i) {
            const int c = w * 4 + i;
            const int r = c * 8 + bRow;
            ld_lds16(Whi + (size_t)(nBase + r) * DIN + k0 + bCol, Bh + c * 512);
            ld_lds16(Wlo + (size_t)(nBase + r) * DIN + k0 + bCol, Bl + c * 512);
        }
        // A: reg-staged, split once per element, swizzled ds_write
#pragma unroll
        for (int it = 0; it < 4; ++it) {
            const int idx = it * 256 + tid;   // granule of 8 f32
            const int r  = idx >> 3;          // 0..127
            const int gl = idx & 7;
            const float* src = X + (size_t)(mBase + r) * DIN + k0 + gl * 8;
            const f32x4 v0 = *(const f32x4*)(src);
            const f32x4 v1 = *(const f32x4*)(src + 4);
            bf16x8 h8, l8;
#pragma unroll
            for (int e = 0; e < 4; ++e) {
                u16 a, b;
                splitf(v0[e], a, b); h8[e] = (short)a; l8[e] = (short)b;
                splitf(v1[e], a, b); h8[e + 4] = (short)a; l8[e + 4] = (short)b;
            }
            const int phys = r * 64 + ((gl ^ (r & 7)) * 8);
            *(bf16x8*)(Ah + phys) = h8;
            *(bf16x8*)(Al + phys) = l8;
        }
        __syncthreads();
#pragma unroll
        for (int ks = 0; ks < 2; ++ks) {
            const int colE = ks * 32 + kg * 8;
            bf16x8 ah[4], al[4], bh[4], bl[4];
#pragma unroll
            for (int f = 0; f < 4; ++f) {
                const int ra = wr * 64 + f * 16 + fr;
                const int pa = ra * 64 + (colE ^ ((fr & 7) << 3));
                ah[f] = *(const bf16x8*)(Ah + pa);
                al[f] = *(const bf16x8*)(Al + pa);
                const int rb = wc * 64 + f * 16 + fr;
                const int pb = rb * 64 + (colE ^ ((fr & 7) << 3));
                bh[f] = *(const bf16x8*)(Bh + pb);
                bl[f] = *(const bf16x8*)(Bl + pb);
            }
#pragma unroll
            for (int i = 0; i < 4; ++i)
#pragma unroll
                for (int j = 0; j < 4; ++j) {
                    acc[i][j] = __builtin_amdgcn_mfma_f32_16x16x32_bf16(ah[i], bh[j], acc[i][j], 0, 0, 0);
                    acc[i][j] = __builtin_amdgcn_mfma_f32_16x16x32_bf16(ah[i], bl[j], acc[i][j], 0, 0, 0);
                    acc[i][j] = __builtin_amdgcn_mfma_f32_16x16x32_bf16(al[i], bh[j], acc[i][j], 0, 0, 0);
                }
        }
        __syncthreads();
    }

    // epilogue: acc -> scan tile (C/D layout: col=lane&15, row=(lane>>4)*4+rg)
#pragma unroll
    for (int i = 0; i < 4; ++i)
#pragma unroll
        for (int j = 0; j < 4; ++j)
#pragma unroll
            for (int rg = 0; rg < 4; ++rg)
                st[(wr * 64 + i * 16 + kg * 4 + rg) * 132 + wc * 64 + j * 16 + fr]
                    = acc[i][j][rg];
    __syncthreads();

    // --- segmented scan along t: 8 segments of 16 rows, x4-vectorized ---
    // thread = (segment sseg, 4-col group cg)
    const int sseg = tid >> 5;              // 0..7
    const int cg   = (tid & 31) * 4;        // col base within 128-col slice
    const f32x4 wv4 = *(const f32x4*)(wdiag + nBase + cg);

    // phase 1: in-register scan of one 16-row segment x 4 cols
    f32x4 rr[16];
    {
        f32x4 run = (f32x4){0.f, 0.f, 0.f, 0.f};
#pragma unroll
        for (int i = 0; i < 16; ++i) {
            const f32x4 v = *(const f32x4*)&st[(sseg * 16 + i) * 132 + cg];
#pragma unroll
            for (int e = 0; e < 4; ++e) run[e] = fmaf(wv4[e], run[e], v[e]);
            rr[i] = run;
        }
        *(f32x4*)&segT[sseg * 128 + cg] = run;
    }
    __syncthreads();

    // phase 2: scan the 8 segment totals (factor w^16), emit carries + L
    if (tid < 32) {
        const int c4 = tid * 4;
        const f32x4 w16 = *(const f32x4*)(wpow + 15 * HID + nBase + c4);
        f32x4 c = (f32x4){0.f, 0.f, 0.f, 0.f};
#pragma unroll
        for (int s2 = 0; s2 < 8; ++s2) {
            *(f32x4*)&segC[s2 * 128 + c4] = c;
            const f32x4 tv = *(const f32x4*)&segT[s2 * 128 + c4];
#pragma unroll
            for (int e = 0; e < 4; ++e) c[e] = fmaf(w16[e], c[e], tv[e]);
        }
        const int cI = (mBase >> 7) & (NCHUNK - 1);
        const int bI = mBase >> 12;
        *(f32x4*)&L[(cI * BATCH + bI) * HID + nBase + c4] = c;   // chunk-final
    }
    __syncthreads();

    // phase 3: apply segment carry, write BF16 chunk-local state (u16x4, 8B)
    {
        const f32x4 cin = *(const f32x4*)&segC[sseg * 128 + cg];
        f32x4 p = wv4;                        // w^(i+1)
        u16* dst = localbf + (size_t)(mBase + sseg * 16) * HID + nBase + cg;
#pragma unroll
        for (int i = 0; i < 16; ++i) {
            u16x4 ob;
#pragma unroll
            for (int e = 0; e < 4; ++e)
                ob[e] = f2bf_rne(fmaf(p[e], cin[e], rr[i][e]));
            *(u16x4*)(dst + (size_t)i * HID) = ob;
#pragma unroll
            for (int e = 0; e < 4; ++e) p[e] *= wv4[e];
        }
    }
}

// ---------------------------------------------------------------------------
// carry across chunks: carry[c][b][h] = state entering chunk c
// ---------------------------------------------------------------------------
__global__ __launch_bounds__(256) void scan_carry(
        const float* __restrict__ L, const float* __restrict__ wpow,
        float* __restrict__ carry) {
    const int idx = blockIdx.x * 256 + threadIdx.x;   // 8192
    const int h = idx & (HID - 1);
    const int b = idx >> 9;
    const float wf = wpow[(CLEN - 1) * HID + h];      // w^128
    float H = 0.f;
    for (int c = 0; c < NCHUNK; ++c) {
        const int o = (c * BATCH + b) * HID + h;
        carry[o] = H;
        H = fmaf(wf, H, L[o]);
    }
}

// ---------------------------------------------------------------------------
// GEMM2 with fused fix: out = (local_bf16 + w^(tl+1)*carry) @ W_out^T.
// B global_load_lds issued first; A reg-staged (bf16 load -> f32 fix -> split).
// Grid: 1024 linear, XCD-swizzled. (~80% MFMA-pipe-bound, structural ceiling)
// ---------------------------------------------------------------------------
__global__ __launch_bounds__(256, 2) void gemm2_fix(
        const u16* __restrict__ localbf, const u16* __restrict__ Bhi_g,
        const u16* __restrict__ Blo_g, const float* __restrict__ wpow,
        const float* __restrict__ carry, float* __restrict__ C) {
    __shared__ __align__(16) char smem[65536];
    u16* Ah = (u16*)smem;                   // [128][64] swizzled (16KB)
    u16* Al = (u16*)(smem + 16384);
    u16* Bh = (u16*)(smem + 32768);
    u16* Bl = (u16*)(smem + 49152);

    const int tid  = threadIdx.x;
    const int w    = tid >> 6;
    const int lane = tid & 63;

    const int bid  = blockIdx.x;
    const int xcd  = bid & 7;
    const int slot = bid >> 3;              // 0..127
    const int mBase = (xcd * 64 + (slot >> 1)) * 128;
    const int nBase = (slot & 1) * 128;

    const int wr = w >> 1, wc = w & 1;
    const int fr = lane & 15;
    const int kg = lane >> 4;

    const int bRow = lane >> 3;
    const int bCol = ((lane & 7) ^ bRow) * 8;

    // fix constants: whole m-tile is one (chunk, batch)
    const int cI = (mBase >> 7) & (NCHUNK - 1);
    const int bI = mBase >> 12;
    const float* crow = carry + (size_t)(cI * BATCH + bI) * HID;

    f32x4 acc[4][4];
#pragma unroll
    for (int i = 0; i < 4; ++i)
#pragma unroll
        for (int j = 0; j < 4; ++j) acc[i][j] = (f32x4){0.f, 0.f, 0.f, 0.f};

    for (int k0 = 0; k0 < HID; k0 += 64) {
        // B: async global->LDS FIRST (latency hides under A staging)
#pragma unroll
        for (int i = 0; i < 4; ++i) {
            const int c = w * 4 + i;
            const int r2 = c * 8 + bRow;
            ld_lds16(Bhi_g + (size_t)(nBase + r2) * HID + k0 + bCol, Bh + c * 512);
            ld_lds16(Blo_g + (size_t)(nBase + r2) * HID + k0 + bCol, Bl + c * 512);
        }
        // A: reg-staged, bf16 load + fix + split fused
#pragma unroll
        for (int it = 0; it < 4; ++it) {
            const int idx = it * 256 + tid;   // 0..1023 granules of 8 bf16
            const int r  = idx >> 3;          // 0..127 (tl == r)
            const int gl = idx & 7;
            const int gm = mBase + r;
            const size_t col = (size_t)(k0 + gl * 8);
            const bf16x8 lv = *(const bf16x8*)(localbf + (size_t)gm * HID + col);
            const f32x4 p0 = *(const f32x4*)(wpow + (size_t)r * HID + col);
            const f32x4 p1 = *(const f32x4*)(wpow + (size_t)r * HID + col + 4);
            const f32x4 c0 = *(const f32x4*)(crow + col);
            const f32x4 c1 = *(const f32x4*)(crow + col + 4);
            bf16x8 h8, l8;
#pragma unroll
            for (int e = 0; e < 4; ++e) {
                const float f0 = fmaf(p0[e], c0[e], bf2f((u16)lv[e]));
                const float f1 = fmaf(p1[e], c1[e], bf2f((u16)lv[e + 4]));
                u16 a, b;
                splitf(f0, a, b); h8[e] = (short)a; l8[e] = (short)b;
                splitf(f1, a, b); h8[e + 4] = (short)a; l8[e + 4] = (short)b;
            }
            const int phys = r * 64 + ((gl ^ (r & 7)) * 8);
            *(bf16x8*)(Ah + phys) = h8;
            *(bf16x8*)(Al + phys) = l8;
        }
        __syncthreads();
#pragma unroll
        for (int ks = 0; ks < 2; ++ks) {
            const int colE = ks * 32 + kg * 8;
            bf16x8 ah[4], al[4], bh[4], bl[4];
#pragma unroll
            for (int f = 0; f < 4; ++f) {
                const int ra = wr * 64 + f * 16 + fr;
                const int pa = ra * 64 + (colE ^ ((fr & 7) << 3));
                ah[f] = *(const bf16x8*)(Ah + pa);
                al[f] = *(const bf16x8*)(Al + pa);
                const int rb = wc * 64 + f * 16 + fr;
                const int pb = rb * 64 + (colE ^ ((fr & 7) << 3));
                bh[f] = *(const bf16x8*)(Bh + pb);
                bl[f] = *(const bf16x8*)(Bl + pb);
            }
#pragma unroll
            for (int i = 0; i < 4; ++i)
#pragma unroll
                for (int j = 0; j < 4; ++j) {
                    acc[i][j] = __builtin_amdgcn_mfma_f32_16x16x32_bf16(ah[i], bh[j], acc[i][j], 0, 0, 0);
                    acc[i][j] = __builtin_amdgcn_mfma_f32_16x16x32_bf16(ah[i], bl[j], acc[i][j], 0, 0, 0);
                    acc[i][j] = __builtin_amdgcn_mfma_f32_16x16x32_bf16(al[i], bh[j], acc[i][j], 0, 0, 0);
                }
        }
        __syncthreads();
    }

#pragma unroll
    for (int i = 0; i < 4; ++i) {
        const size_t row0 = (size_t)mBase + wr * 64 + i * 16 + kg * 4;
#pragma unroll
        for (int j = 0; j < 4; ++j) {
            const int col = nBase + wc * 64 + j * 16 + fr;
#pragma unroll
            for (int rg = 0; rg < 4; ++rg)
                C[(row0 + rg) * DOUT + col] = acc[i][j][rg];
        }
    }
}

// ---------------------------------------------------------------------------
extern "C" void kernel_launch(void* const* d_in, const int* in_sizes, int n_in,
                              void* d_out, int out_size, void* d_ws, size_t ws_size,
                              hipStream_t stream) {
    const float* x     = (const float*)d_in[0];   // [16,4096,256]
    const float* W_in  = (const float*)d_in[1];   // [512,256]
    const float* W_h   = (const float*)d_in[2];   // [512,512] (diagonal)
    const float* W_out = (const float*)d_in[3];   // [256,512]
    float* out = (float*)d_out;                    // [16,4096,256]

    // workspace layout
    char* ws = (char*)d_ws;
    u16*   localbf = (u16*)(ws);                       // 67,108,864 (bf16 local state)
    float* L       = (float*)(ws + 134217728);         // 1,048,576
    float* carry   = (float*)(ws + 135266304);         // 1,048,576
    float* wpow    = (float*)(ws + 136314880);         // 262,144
    float* wdiag   = (float*)(ws + 136577024);         // 2,048
    u16*   Winhi   = (u16*)(ws + 136579072);           // 262,144
    u16*   Winlo   = (u16*)(ws + 136841216);           // 262,144
    u16*   Wouthi  = (u16*)(ws + 137103360);           // 262,144
    u16*   Woutlo  = (u16*)(ws + 137365504);           // 262,144

    prep<<<257, 256, 0, stream>>>(W_h, W_in, W_out, wdiag, wpow,
                                  Winhi, Winlo, Wouthi, Woutlo);
    gemm1_scan<<<2048, 256, 0, stream>>>(x, Winhi, Winlo, localbf, L, wdiag, wpow);
    scan_carry<<<32, 256, 0, stream>>>(L, wpow, carry);
    gemm2_fix<<<1024, 256, 0, stream>>>(localbf, Wouthi, Woutlo, wpow, carry, out);
}